// Round 1
// baseline (77.631 us; speedup 1.0000x reference)
//
#include <hip/hip_runtime.h>

// SampledSoftmaxLoss: N=51200 rows, D=64, K=100 negatives, V=100001 items.
// loss = sum_n w_n * (logsumexp(logits_n) - pos_logit_n) / sum_n w_n
// logits = cos_sim(vo_n, item_idx) / 0.05
//
// Pass 1 normalizes the item table into an fp8-e4m3 [V][64B] copy in ws
// (6.4 MB -> ~62% L2 hit, misses served by L3). Pass 2: one wave per row,
// 16 groups x 4 lanes.
//
// r7: gather-latency theory. r5/r6 issued the 7 table gathers and consumed
// them in the SAME iteration (only ~20 insts of stream-prefetch between
// issue and use) -> every row exposed an L2-miss/L3-hit latency; VALUBusy
// was 49% with a nominally full grid. Now the pipeline is one stage
// deeper: resolve + issue row i+1's gathers BEFORE computing row i.
//   - idx streams (tgt/negi): loaded 2 rows ahead, single buffer (dead
//     right after resolve, reloaded same iteration).
//   - query/wgt + rb gather buffers: ping-pong via 2x-unrolled loop (no
//     rotation movs).
// VGPR ~56 -> ~120: launch_bounds(256,3) (generous cap; r6 showed a
// tight cap spills), grid 2048 -> 1024 blocks (4096 waves = 4/SIMD
// residency, 12.5 rows/wave).

#define D_DIM 64
#define K_NEG 100
#define INV_TEMP 20.0f
#define MAX_LOGIT 20.0f
#define LOG2E 1.4426950408889634f
#define LN2 0.6931471805599453f

#define NBLK_MAIN 1024
#define NBLK_NORM 512
#define NT 7   // ceil(101/16) steps of 16 logits

typedef float fv2 __attribute__((ext_vector_type(2)));

// ---------------- Pass 1: normalize item table -> fp8 e4m3 ----------------
__global__ __launch_bounds__(256) void normalize_kernel(
    const float* __restrict__ items, unsigned int* __restrict__ tab, int V) {
  const int lane = threadIdx.x & 63;
  const int wid  = threadIdx.x >> 6;
  const int g = lane >> 4, q = lane & 15;
  const int waveId = blockIdx.x * 4 + wid;
  const int nWaves = gridDim.x * 4;
  for (int base = waveId * 4; base < V; base += nWaves * 4) {
    const int r = base + g;
    const bool act = (r < V);
    float4 x = make_float4(0.f, 0.f, 0.f, 0.f);
    if (act) x = *reinterpret_cast<const float4*>(items + (size_t)r * D_DIM + q * 4);
    float ss = x.x * x.x + x.y * x.y + x.z * x.z + x.w * x.w;
    ss += __shfl_xor(ss, 1);
    ss += __shfl_xor(ss, 2);
    ss += __shfl_xor(ss, 4);
    ss += __shfl_xor(ss, 8);
    const float inv = 1.0f / fmaxf(sqrtf(ss), 1e-12f);
    if (act) {
      int u = 0;
      u = __builtin_amdgcn_cvt_pk_fp8_f32(x.x * inv, x.y * inv, u, false);
      u = __builtin_amdgcn_cvt_pk_fp8_f32(x.z * inv, x.w * inv, u, true);
      tab[(size_t)r * 16 + q] = (unsigned int)u;
    }
  }
}

// ---------------- Pass 2: main loss ----------------
// one wave per row; 16 groups x 4 lanes; group g handles logit j = t*16+g.

struct Idx { int t, n0, n1, n2, n3, n4, n5, n6; };
struct Qry { float4 a0, a1, a2, a3; float w; };

__device__ __forceinline__ void load_idx(Idx& ix, const int* __restrict__ tgt,
                                         const int* __restrict__ negi,
                                         int row, int g) {
  ix.t = tgt[row];
  const int* __restrict__ nrow = negi + (size_t)row * K_NEG;
  ix.n0 = 0;
  ix.n6 = 0;
  if (g >= 1) ix.n0 = nrow[g - 1];
  ix.n1 = nrow[16 + g - 1];
  ix.n2 = nrow[32 + g - 1];
  ix.n3 = nrow[48 + g - 1];
  ix.n4 = nrow[64 + g - 1];
  ix.n5 = nrow[80 + g - 1];
  if (g <= 4) ix.n6 = nrow[96 + g - 1];
}

__device__ __forceinline__ void load_qry(Qry& Q, const float* __restrict__ oe,
                                         const float* __restrict__ wgt,
                                         int row, int q) {
  const float* __restrict__ orow = oe + (size_t)row * D_DIM + q * 16;
  Q.a0 = *reinterpret_cast<const float4*>(orow + 0);
  Q.a1 = *reinterpret_cast<const float4*>(orow + 4);
  Q.a2 = *reinterpret_cast<const float4*>(orow + 8);
  Q.a3 = *reinterpret_cast<const float4*>(orow + 12);
  Q.w  = wgt[row];
}

// resolve collision-free indices for `row` and issue all 7 table gathers.
// alt indices only loaded on rare collision (execz-skipped).
__device__ __forceinline__ void resolve_gather(
    const Idx& ix, const unsigned int* __restrict__ tab,
    const int* __restrict__ alti, int row, int g, int q, uint4 (&rb)[NT]) {
  const int* __restrict__ arow = alti + (size_t)row * K_NEG;
  int id[NT];
  {
    int v0 = (g == 0) ? ix.t : ix.n0;
    if (g >= 1 && v0 == ix.t) v0 = arow[g - 1];
    id[0] = v0;
    int v1 = ix.n1; if (v1 == ix.t) v1 = arow[16 + g - 1]; id[1] = v1;
    int v2 = ix.n2; if (v2 == ix.t) v2 = arow[32 + g - 1]; id[2] = v2;
    int v3 = ix.n3; if (v3 == ix.t) v3 = arow[48 + g - 1]; id[3] = v3;
    int v4 = ix.n4; if (v4 == ix.t) v4 = arow[64 + g - 1]; id[4] = v4;
    int v5 = ix.n5; if (v5 == ix.t) v5 = arow[80 + g - 1]; id[5] = v5;
    int v6 = 0;
    if (g <= 4) { v6 = ix.n6; if (v6 == ix.t) v6 = arow[96 + g - 1]; }
    id[6] = v6;
  }
#pragma unroll
  for (int t = 0; t < NT; ++t)
    rb[t] = *reinterpret_cast<const uint4*>(tab + (size_t)id[t] * 16 + q * 4);
}

// packed fv2 dot products -> v_pk_fma_f32; per-group 4-lane reduce; lse.
__device__ __forceinline__ void compute_row(const Qry& Q, const uint4 (&rb)[NT],
                                            float& num, float& den,
                                            int lane, int g, int q) {
  const fv2 qa0 = {Q.a0.x, Q.a0.y}, qa1 = {Q.a0.z, Q.a0.w};
  const fv2 qa2 = {Q.a1.x, Q.a1.y}, qa3 = {Q.a1.z, Q.a1.w};
  const fv2 qa4 = {Q.a2.x, Q.a2.y}, qa5 = {Q.a2.z, Q.a2.w};
  const fv2 qa6 = {Q.a3.x, Q.a3.y}, qa7 = {Q.a3.z, Q.a3.w};

  fv2 ss2 = qa0 * qa0;
  ss2 += qa1 * qa1;
  ss2 += qa2 * qa2;
  ss2 += qa3 * qa3;
  ss2 += qa4 * qa4;
  ss2 += qa5 * qa5;
  ss2 += qa6 * qa6;
  ss2 += qa7 * qa7;
  float ss = ss2[0] + ss2[1];
  ss += __shfl_xor(ss, 1);
  ss += __shfl_xor(ss, 2);
  const float inv_o = 1.0f / fmaxf(sqrtf(ss), 1e-12f);
  const float scale = inv_o * INV_TEMP;   // fold: one mult per logit

  float sumexp = 0.f;
  float pos_logit = 0.f;

#pragma unroll
  for (int t = 0; t < NT; ++t) {
    const uint4 r = rb[t];
    fv2 acc;
    acc  = qa0 * __builtin_amdgcn_cvt_pk_f32_fp8((int)r.x, false);
    acc += qa1 * __builtin_amdgcn_cvt_pk_f32_fp8((int)r.x, true);
    acc += qa2 * __builtin_amdgcn_cvt_pk_f32_fp8((int)r.y, false);
    acc += qa3 * __builtin_amdgcn_cvt_pk_f32_fp8((int)r.y, true);
    acc += qa4 * __builtin_amdgcn_cvt_pk_f32_fp8((int)r.z, false);
    acc += qa5 * __builtin_amdgcn_cvt_pk_f32_fp8((int)r.z, true);
    acc += qa6 * __builtin_amdgcn_cvt_pk_f32_fp8((int)r.w, false);
    acc += qa7 * __builtin_amdgcn_cvt_pk_f32_fp8((int)r.w, true);
    float p = acc[0] + acc[1];
    p += __shfl_xor(p, 1);
    p += __shfl_xor(p, 2);
    const int j = t * 16 + g;
    if (q == 0 && j <= K_NEG) {
      const float logit = p * scale;
      sumexp += exp2f((logit - MAX_LOGIT) * LOG2E);
      if (j == 0) pos_logit = logit;  // lane 0 only
    }
  }
  sumexp += __shfl_xor(sumexp, 4);
  sumexp += __shfl_xor(sumexp, 8);
  sumexp += __shfl_xor(sumexp, 16);
  sumexp += __shfl_xor(sumexp, 32);
  if (lane == 0) {
    const float lse = log2f(sumexp) * LN2 + MAX_LOGIT;
    const float loss = lse - pos_logit;
    if (Q.w > 0.f) {
      num += loss * Q.w;
      den += Q.w;
    }
  }
}

__global__ __launch_bounds__(256, 3) void loss_kernel(
    const float* __restrict__ oe,      // [N,64]
    const int*   __restrict__ tgt,     // [N]
    const unsigned int* __restrict__ tab, // [V][16] uints of packed fp8
    const float* __restrict__ wgt,     // [N]
    const int*   __restrict__ negi,    // [N,100]
    const int*   __restrict__ alti,    // [N,100]
    float2*      __restrict__ partials,// [gridDim.x]
    int N) {
  const int lane = threadIdx.x & 63;
  const int wid  = threadIdx.x >> 6;
  const int g = lane >> 2, q = lane & 3;
  const int waveId = blockIdx.x * 4 + wid;
  const int nWaves = gridDim.x * 4;

  float num = 0.f, den = 0.f;

  int row = waveId;
  Idx  ix;                 // idx streams for row+1 (single buffer)
  Qry  qA, qB;             // query/wgt ping-pong
  uint4 rbA[NT], rbB[NT];  // gather ping-pong

  // ---- prologue: fill the pipe for the wave's first row ----
  if (row < N) {
    load_idx(ix, tgt, negi, row, g);
    load_qry(qA, oe, wgt, row, q);
    resolve_gather(ix, tab, alti, row, g, q, rbA);  // only exposed gather wait
    const int r1 = row + nWaves;
    if (r1 < N) {
      load_idx(ix, tgt, negi, r1, g);
      load_qry(qB, oe, wgt, r1, q);
    }
  }

  // steady state per half-iter (computing row r):
  //   1. resolve idx(r+1) [ix loaded a full row ago] + issue gathers(r+1)
  //   2. issue idx loads (r+2) into ix (dead after step 1)
  //   3. compute row r from resident regs (gathers issued a full row ago)
  //   4. issue query/wgt loads (r+2) into the buffer compute just freed
  while (row < N) {
    {  // half A: compute qA/rbA, prep rbB
      const int r1 = row + nWaves;
      const int r2 = r1 + nWaves;
      if (r1 < N) resolve_gather(ix, tab, alti, r1, g, q, rbB);
      if (r2 < N) load_idx(ix, tgt, negi, r2, g);
      compute_row(qA, rbA, num, den, lane, g, q);
      if (r2 < N) load_qry(qA, oe, wgt, r2, q);
    }
    row += nWaves;
    if (row >= N) break;
    {  // half B: roles swapped
      const int r1 = row + nWaves;
      const int r2 = r1 + nWaves;
      if (r1 < N) resolve_gather(ix, tab, alti, r1, g, q, rbA);
      if (r2 < N) load_idx(ix, tgt, negi, r2, g);
      compute_row(qB, rbB, num, den, lane, g, q);
      if (r2 < N) load_qry(qB, oe, wgt, r2, q);
    }
    row += nWaves;
  }

  __shared__ float2 red[4];
  if (lane == 0) red[wid] = make_float2(num, den);
  __syncthreads();
  if (threadIdx.x == 0) {
    float n = 0.f, d = 0.f;
#pragma unroll
    for (int i = 0; i < 4; ++i) { n += red[i].x; d += red[i].y; }
    partials[blockIdx.x] = make_float2(n, d);
  }
}

// ---------------- Pass 3: final reduce ----------------
__global__ __launch_bounds__(256) void finish_kernel(
    const float2* __restrict__ partials, int nblk, float* __restrict__ out) {
  float num = 0.f, den = 0.f;
  for (int i = threadIdx.x; i < nblk; i += 256) {
    const float2 p = partials[i];
    num += p.x;
    den += p.y;
  }
#pragma unroll
  for (int m = 1; m < 64; m <<= 1) {
    num += __shfl_xor(num, m);
    den += __shfl_xor(den, m);
  }
  __shared__ float2 red[4];
  const int wid = threadIdx.x >> 6;
  const int lane = threadIdx.x & 63;
  if (lane == 0) red[wid] = make_float2(num, den);
  __syncthreads();
  if (threadIdx.x == 0) {
    float n = 0.f, d = 0.f;
#pragma unroll
    for (int i = 0; i < 4; ++i) { n += red[i].x; d += red[i].y; }
    out[0] = n / d;
  }
}

extern "C" void kernel_launch(void* const* d_in, const int* in_sizes, int n_in,
                              void* d_out, int out_size, void* d_ws, size_t ws_size,
                              hipStream_t stream) {
  const float* oe    = (const float*)d_in[0];  // output_embeddings [B,S,64]
  const int*   tgt   = (const int*)  d_in[1];  // target_ids [B,S]
  const float* items = (const float*)d_in[2];  // all_item_embeddings [V,64]
  const float* wgt   = (const float*)d_in[3];  // supervision_weights [B,S]
  const int*   negi  = (const int*)  d_in[4];  // neg_indices [N,100]
  const int*   alti  = (const int*)  d_in[5];  // alt_neg_indices [N,100]

  const int N = in_sizes[0] / D_DIM;  // 51200
  const int V = in_sizes[2] / D_DIM;  // 100001

  unsigned int* tab = (unsigned int*)d_ws;                    // V*16 uints (6.4 MB)
  size_t off = ((size_t)V * 16 * sizeof(unsigned int) + 255) & ~(size_t)255;
  float2* partials = (float2*)((char*)d_ws + off);            // NBLK_MAIN float2

  normalize_kernel<<<NBLK_NORM, 256, 0, stream>>>(items, tab, V);
  loss_kernel<<<NBLK_MAIN, 256, 0, stream>>>(oe, tgt, tab, wgt, negi, alti,
                                             partials, N);
  finish_kernel<<<1, 256, 0, stream>>>(partials, NBLK_MAIN, (float*)d_out);
}